// Round 3
// baseline (462.461 us; speedup 1.0000x reference)
//
#include <hip/hip_runtime.h>
#include <math.h>

// FanoCoupling, round 5: distance-2 software pipeline on the round-4 structure.
//
// Round-4 left ~45% of achievable BW on the table with near-ideal traffic and
// 0 bank conflicts -> pure latency stall: the 1-deep T14 split issued tile
// T+1's loads at body-top and waited for them (ds_write vmcnt) at body-end of
// the SAME body. At saturated-HBM latency the whole block drained every tile.
//
// Round 5: classic 2-deep rotate --
//   body(T): issue loads(T+2) -> stgN          (7 NT loads in flight)
//            compute T from buf[cur]           (ds_read + MFMA + fold)
//            ds_write stgP (=T+1, issued one FULL body ago) -> buf[cur^1]
//            barrier; stgP=stgN; rotate
// The compiler's in-order vmcnt tracking turns the ds_write wait into a
// counted vmcnt (T+2's loads stay in flight across the barrier) = T4 pattern.
// Colony-6 residual prefetched at distance 1. All streaming traffic is
// nontemporal (each S/out byte touched exactly once; W/bias stay cached).
//
//   LDS: [2][c:6][b:16][slot:16][4] f32, slot XOR-swizzled (= unit ^ row),
//   48 KiB -> 3 blocks/CU. One barrier per tile.
//   wave w owns z rows [w*16,w*16+16): wf[4] hoisted from global,
//   16 MFMAs/tile -> 8 slots U0,U1,U3,U4,V1,V2,V3,V5; D: lane=batch, 4 z.
//
// Lines: O2=s2+g0*(U0+V1+b)  O4=s4+g1*(U0+V3+b)
//        O5=s5+g3*(U1+V3+b)+g6*(U4+V2+b)
//        O6=s6+g2*(U0+V5+b)+g4*(U4+V1+b)+g5*(U3+V2+b)
//        O0,O1,O3 = copies.

using bf16x8  = __attribute__((ext_vector_type(8))) __bf16;
using floatx4 = __attribute__((ext_vector_type(4))) float;

__device__ __forceinline__ bf16x8 cvt8(floatx4 a, floatx4 b) {
    bf16x8 r;
    r[0]=(__bf16)a[0]; r[1]=(__bf16)a[1]; r[2]=(__bf16)a[2]; r[3]=(__bf16)a[3];
    r[4]=(__bf16)b[0]; r[5]=(__bf16)b[1]; r[6]=(__bf16)b[2]; r[7]=(__bf16)b[3];
    return r;
}

// float index of 16B unit (c, row, slot) in one LDS buffer
#define LDSF(c, row, slot) ((((c) << 8) | ((row) << 4) | (slot)) << 2)

__global__ __launch_bounds__(256, 3)
void fano_kernel(const float* __restrict__ S,
                 const float* __restrict__ W,
                 const float* __restrict__ bias,
                 const float* __restrict__ gates,
                 float* __restrict__ out, int nt)
{
    __shared__ float buf[2][6144];    // 48 KiB total

    const int tid  = threadIdx.x;
    const int lane = tid & 63;
    const int w    = tid >> 6;        // wave = z-quarter
    const int nl   = lane & 15;       // batch (frag n / copy unit)
    const int qg   = lane >> 4;       // k-quad / batch-subrow
    const int bq   = w * 4 + qg;      // staging/copy batch row; ALSO z-quad idx

    // ---- gates softmax (uniform) ----
    float g[7];
    {
        float mx = gates[0];
        #pragma unroll
        for (int i = 1; i < 7; ++i) mx = fmaxf(mx, gates[i]);
        float se = 0.f;
        #pragma unroll
        for (int i = 0; i < 7; ++i) { g[i] = __expf(gates[i] - mx); se += g[i]; }
        const float inv = 1.f / se;
        #pragma unroll
        for (int i = 0; i < 7; ++i) g[i] *= inv;
    }

    // ---- bias frag: z = w*16 + qg*4 + r = bq*4 + r ----
    const floatx4 bv = *(const floatx4*)(bias + bq * 4);

    // ---- W frags (A operand), hoisted: lane holds z=w*16+nl, k=h*32+qg*8+j ----
    bf16x8 wf[4];
    #pragma unroll
    for (int h = 0; h < 4; ++h) {
        const float* p = W + (w * 16 + nl) * 128 + h * 32 + qg * 8;
        wf[h] = cvt8(*(const floatx4*)p, *(const floatx4*)(p + 4));
    }

    const long long st = gridDim.x;
    long long tile = blockIdx.x;
    if (tile >= nt) return;
    int cur = 0;

    // ---- prologue: stage tile into buf[0]; issue tile+st loads + res6(tile) ----
    {
        const float* sp = S + tile * 7168 + bq * 448;
        #pragma unroll
        for (int c = 0; c < 6; ++c) {
            floatx4 v = __builtin_nontemporal_load((const floatx4*)(sp + c * 64 + nl * 4));
            *(floatx4*)(&buf[0][LDSF(c, bq, nl ^ bq)]) = v;
        }
    }
    floatx4 stgP[6];
    if (tile + st < (long long)nt) {
        const float* sp = S + (tile + st) * 7168 + bq * 448;
        #pragma unroll
        for (int c = 0; c < 6; ++c)
            stgP[c] = __builtin_nontemporal_load((const floatx4*)(sp + c * 64 + nl * 4));
    }
    floatx4 res6C = __builtin_nontemporal_load(
        (const floatx4*)(S + tile * 7168 + nl * 448 + 384 + bq * 4));
    __syncthreads();

    for (;;) {
        const long long nxt1 = tile + st;
        const long long nxt2 = tile + 2 * st;
        const bool has1 = nxt1 < (long long)nt;
        const bool has2 = nxt2 < (long long)nt;
        const long long tb = tile * 7168;

        // -- issue distance-2 loads (in flight across this body AND the barrier) --
        floatx4 stgN[6];
        if (has2) {
            const float* sp = S + nxt2 * 7168 + bq * 448;
            #pragma unroll
            for (int c = 0; c < 6; ++c)
                stgN[c] = __builtin_nontemporal_load((const floatx4*)(sp + c * 64 + nl * 4));
        }
        // -- distance-1 colony-6 residual for the NEXT body --
        floatx4 res6N;
        if (has1)
            res6N = __builtin_nontemporal_load(
                (const floatx4*)(S + nxt1 * 7168 + nl * 448 + 384 + bq * 4));

        const float* bc = buf[cur];

        // -- copies {0,1,3}: LDS -> coalesced NT store (issued before MFMA) --
        #pragma unroll
        for (int j = 0; j < 3; ++j) {
            const int c = (j == 2) ? 3 : j;
            floatx4 v = *(const floatx4*)(bc + LDSF(c, bq, nl ^ bq));
            __builtin_nontemporal_store(v, (floatx4*)(out + tb + bq * 448 + c * 64 + nl * 4));
        }

        // -- MFMA: 2 k-phases, B-frags from swizzled LDS --
        floatx4 acc[8];
        #pragma unroll
        for (int s8 = 0; s8 < 8; ++s8) acc[s8] = (floatx4){0.f, 0.f, 0.f, 0.f};
        #pragma unroll
        for (int kb = 0; kb < 2; ++kb) {
            bf16x8 sb[6];
            const int u0 = kb * 8 + qg * 2;
            #pragma unroll
            for (int c = 0; c < 6; ++c) {
                floatx4 f0 = *(const floatx4*)(bc + LDSF(c, nl, (u0    ) ^ nl));
                floatx4 f1 = *(const floatx4*)(bc + LDSF(c, nl, (u0 + 1) ^ nl));
                sb[c] = cvt8(f0, f1);
            }
            acc[0] = __builtin_amdgcn_mfma_f32_16x16x32_bf16(wf[kb],     sb[0], acc[0], 0,0,0);
            acc[1] = __builtin_amdgcn_mfma_f32_16x16x32_bf16(wf[kb],     sb[1], acc[1], 0,0,0);
            acc[2] = __builtin_amdgcn_mfma_f32_16x16x32_bf16(wf[kb],     sb[3], acc[2], 0,0,0);
            acc[3] = __builtin_amdgcn_mfma_f32_16x16x32_bf16(wf[kb],     sb[4], acc[3], 0,0,0);
            acc[4] = __builtin_amdgcn_mfma_f32_16x16x32_bf16(wf[2 + kb], sb[1], acc[4], 0,0,0);
            acc[5] = __builtin_amdgcn_mfma_f32_16x16x32_bf16(wf[2 + kb], sb[2], acc[5], 0,0,0);
            acc[6] = __builtin_amdgcn_mfma_f32_16x16x32_bf16(wf[2 + kb], sb[3], acc[6], 0,0,0);
            acc[7] = __builtin_amdgcn_mfma_f32_16x16x32_bf16(wf[2 + kb], sb[5], acc[7], 0,0,0);
        }

        // -- residuals {2,4,5} in acc layout (row=nl batch, unit=bq z-quad) --
        const floatx4 r2 = *(const floatx4*)(bc + LDSF(2, nl, bq ^ nl));
        const floatx4 r4 = *(const floatx4*)(bc + LDSF(4, nl, bq ^ nl));
        const floatx4 r5 = *(const floatx4*)(bc + LDSF(5, nl, bq ^ nl));

        // -- fold + GEMV stores (16 x 64B full segments per instr) --
        floatx4 o2 = r2    + g[0] * (acc[0] + acc[4] + bv);
        floatx4 o4 = r4    + g[1] * (acc[0] + acc[6] + bv);
        floatx4 o5 = r5    + g[3] * (acc[1] + acc[6] + bv)
                           + g[6] * (acc[3] + acc[5] + bv);
        floatx4 o6 = res6C + g[2] * (acc[0] + acc[7] + bv)
                           + g[4] * (acc[3] + acc[4] + bv)
                           + g[5] * (acc[2] + acc[5] + bv);
        float* op = out + tb + nl * 448 + bq * 4;
        __builtin_nontemporal_store(o2, (floatx4*)(op + 2 * 64));
        __builtin_nontemporal_store(o4, (floatx4*)(op + 4 * 64));
        __builtin_nontemporal_store(o5, (floatx4*)(op + 5 * 64));
        __builtin_nontemporal_store(o6, (floatx4*)(op + 6 * 64));

        // -- commit T+1 (issued one full body ago) into the other buffer --
        // compiler emits a counted vmcnt here: T+2's 7 loads stay in flight.
        if (has1) {
            float* bn = buf[cur ^ 1];
            #pragma unroll
            for (int c = 0; c < 6; ++c)
                *(floatx4*)(bn + LDSF(c, bq, nl ^ bq)) = stgP[c];
        }
        __syncthreads();
        if (!has1) break;
        if (has2) {
            #pragma unroll
            for (int c = 0; c < 6; ++c) stgP[c] = stgN[c];
        }
        res6C = res6N;
        tile = nxt1;
        cur ^= 1;
    }
}

extern "C" void kernel_launch(void* const* d_in, const int* in_sizes, int n_in,
                              void* d_out, int out_size, void* d_ws, size_t ws_size,
                              hipStream_t stream) {
    const float* S     = (const float*)d_in[0];   // [B,7,64]
    const float* W     = (const float*)d_in[1];   // [64,128]
    const float* bias  = (const float*)d_in[2];   // [64]
    const float* gates = (const float*)d_in[3];   // [7]
    float* out = (float*)d_out;

    const int B  = in_sizes[0] / (7 * 64);        // 131072
    const int nt = B / 16;                        // 8192 tiles of 16 batches
    int grid = 768;                               // 3 blocks/CU, grid-stride
    if (grid > nt) grid = nt;
    fano_kernel<<<grid, 256, 0, stream>>>(S, W, bias, gates, out, nt);
}

// Round 4
// 456.374 us; speedup vs baseline: 1.0133x; 1.0133x over previous
//
#include <hip/hip_runtime.h>
#include <math.h>

// FanoCoupling, round 6: round-5 distance-2 pipeline, NT STORES REVERTED.
//
// Round-5 lesson (counter smoking gun): nontemporal stores on the scattered
// GEMV outputs (16x64B segments/instr at 1792B row stride) defeated L2
// write-merging -> WRITE_SIZE 232MB -> 533MB (2.3x) -> +57us. NT loads were
// fine (FETCH 204->155MB). So: keep NT loads, use NORMAL stores everywhere
// and let L2 write-allocate merge the 64B segments into full lines again.
//
// Structure (unchanged from round 5):
//   body(T): issue NT loads(T+2) -> stgN       (7 loads in flight)
//            compute T from buf[cur]           (ds_read + MFMA + fold)
//            ds_write stgP (=T+1, issued one FULL body ago) -> buf[cur^1]
//            barrier; stgP=stgN; rotate
//   LDS: [2][c:6][b:16][slot:16][4] f32, slot = unit ^ row (XOR swizzle),
//   48 KiB -> 3 blocks/CU, one barrier per tile.
//   wave w owns z rows [w*16,w*16+16): wf[4] hoisted, 16 MFMAs/tile ->
//   8 slots U0,U1,U3,U4,V1,V2,V3,V5; D layout: lane=batch, 4 consecutive z.
//
// Lines: O2=s2+g0*(U0+V1+b)  O4=s4+g1*(U0+V3+b)
//        O5=s5+g3*(U1+V3+b)+g6*(U4+V2+b)
//        O6=s6+g2*(U0+V5+b)+g4*(U4+V1+b)+g5*(U3+V2+b)
//        O0,O1,O3 = copies.

using bf16x8  = __attribute__((ext_vector_type(8))) __bf16;
using floatx4 = __attribute__((ext_vector_type(4))) float;

__device__ __forceinline__ bf16x8 cvt8(floatx4 a, floatx4 b) {
    bf16x8 r;
    r[0]=(__bf16)a[0]; r[1]=(__bf16)a[1]; r[2]=(__bf16)a[2]; r[3]=(__bf16)a[3];
    r[4]=(__bf16)b[0]; r[5]=(__bf16)b[1]; r[6]=(__bf16)b[2]; r[7]=(__bf16)b[3];
    return r;
}

// float index of 16B unit (c, row, slot) in one LDS buffer
#define LDSF(c, row, slot) ((((c) << 8) | ((row) << 4) | (slot)) << 2)

__global__ __launch_bounds__(256, 3)
void fano_kernel(const float* __restrict__ S,
                 const float* __restrict__ W,
                 const float* __restrict__ bias,
                 const float* __restrict__ gates,
                 float* __restrict__ out, int nt)
{
    __shared__ float buf[2][6144];    // 48 KiB total

    const int tid  = threadIdx.x;
    const int lane = tid & 63;
    const int w    = tid >> 6;        // wave = z-quarter
    const int nl   = lane & 15;       // batch (frag n / copy unit)
    const int qg   = lane >> 4;       // k-quad / batch-subrow
    const int bq   = w * 4 + qg;      // staging/copy batch row; ALSO z-quad idx

    // ---- gates softmax (uniform) ----
    float g[7];
    {
        float mx = gates[0];
        #pragma unroll
        for (int i = 1; i < 7; ++i) mx = fmaxf(mx, gates[i]);
        float se = 0.f;
        #pragma unroll
        for (int i = 0; i < 7; ++i) { g[i] = __expf(gates[i] - mx); se += g[i]; }
        const float inv = 1.f / se;
        #pragma unroll
        for (int i = 0; i < 7; ++i) g[i] *= inv;
    }

    // ---- bias frag: z = w*16 + qg*4 + r = bq*4 + r ----
    const floatx4 bv = *(const floatx4*)(bias + bq * 4);

    // ---- W frags (A operand), hoisted: lane holds z=w*16+nl, k=h*32+qg*8+j ----
    bf16x8 wf[4];
    #pragma unroll
    for (int h = 0; h < 4; ++h) {
        const float* p = W + (w * 16 + nl) * 128 + h * 32 + qg * 8;
        wf[h] = cvt8(*(const floatx4*)p, *(const floatx4*)(p + 4));
    }

    const long long st = gridDim.x;
    long long tile = blockIdx.x;
    if (tile >= nt) return;
    int cur = 0;

    // ---- prologue: stage tile into buf[0]; issue tile+st loads + res6(tile) ----
    {
        const float* sp = S + tile * 7168 + bq * 448;
        #pragma unroll
        for (int c = 0; c < 6; ++c) {
            floatx4 v = __builtin_nontemporal_load((const floatx4*)(sp + c * 64 + nl * 4));
            *(floatx4*)(&buf[0][LDSF(c, bq, nl ^ bq)]) = v;
        }
    }
    floatx4 stgP[6];
    if (tile + st < (long long)nt) {
        const float* sp = S + (tile + st) * 7168 + bq * 448;
        #pragma unroll
        for (int c = 0; c < 6; ++c)
            stgP[c] = __builtin_nontemporal_load((const floatx4*)(sp + c * 64 + nl * 4));
    }
    floatx4 res6C = __builtin_nontemporal_load(
        (const floatx4*)(S + tile * 7168 + nl * 448 + 384 + bq * 4));
    __syncthreads();

    for (;;) {
        const long long nxt1 = tile + st;
        const long long nxt2 = tile + 2 * st;
        const bool has1 = nxt1 < (long long)nt;
        const bool has2 = nxt2 < (long long)nt;
        const long long tb = tile * 7168;

        // -- issue distance-2 loads (in flight across this body AND the barrier) --
        floatx4 stgN[6];
        if (has2) {
            const float* sp = S + nxt2 * 7168 + bq * 448;
            #pragma unroll
            for (int c = 0; c < 6; ++c)
                stgN[c] = __builtin_nontemporal_load((const floatx4*)(sp + c * 64 + nl * 4));
        }
        // -- distance-1 colony-6 residual for the NEXT body --
        floatx4 res6N;
        if (has1)
            res6N = __builtin_nontemporal_load(
                (const floatx4*)(S + nxt1 * 7168 + nl * 448 + 384 + bq * 4));

        const float* bc = buf[cur];

        // -- copies {0,1,3}: LDS -> coalesced store (normal, L2-merged) --
        #pragma unroll
        for (int j = 0; j < 3; ++j) {
            const int c = (j == 2) ? 3 : j;
            floatx4 v = *(const floatx4*)(bc + LDSF(c, bq, nl ^ bq));
            *(floatx4*)(out + tb + bq * 448 + c * 64 + nl * 4) = v;
        }

        // -- MFMA: 2 k-phases, B-frags from swizzled LDS --
        floatx4 acc[8];
        #pragma unroll
        for (int s8 = 0; s8 < 8; ++s8) acc[s8] = (floatx4){0.f, 0.f, 0.f, 0.f};
        #pragma unroll
        for (int kb = 0; kb < 2; ++kb) {
            bf16x8 sb[6];
            const int u0 = kb * 8 + qg * 2;
            #pragma unroll
            for (int c = 0; c < 6; ++c) {
                floatx4 f0 = *(const floatx4*)(bc + LDSF(c, nl, (u0    ) ^ nl));
                floatx4 f1 = *(const floatx4*)(bc + LDSF(c, nl, (u0 + 1) ^ nl));
                sb[c] = cvt8(f0, f1);
            }
            acc[0] = __builtin_amdgcn_mfma_f32_16x16x32_bf16(wf[kb],     sb[0], acc[0], 0,0,0);
            acc[1] = __builtin_amdgcn_mfma_f32_16x16x32_bf16(wf[kb],     sb[1], acc[1], 0,0,0);
            acc[2] = __builtin_amdgcn_mfma_f32_16x16x32_bf16(wf[kb],     sb[3], acc[2], 0,0,0);
            acc[3] = __builtin_amdgcn_mfma_f32_16x16x32_bf16(wf[kb],     sb[4], acc[3], 0,0,0);
            acc[4] = __builtin_amdgcn_mfma_f32_16x16x32_bf16(wf[2 + kb], sb[1], acc[4], 0,0,0);
            acc[5] = __builtin_amdgcn_mfma_f32_16x16x32_bf16(wf[2 + kb], sb[2], acc[5], 0,0,0);
            acc[6] = __builtin_amdgcn_mfma_f32_16x16x32_bf16(wf[2 + kb], sb[3], acc[6], 0,0,0);
            acc[7] = __builtin_amdgcn_mfma_f32_16x16x32_bf16(wf[2 + kb], sb[5], acc[7], 0,0,0);
        }

        // -- residuals {2,4,5} in acc layout (row=nl batch, unit=bq z-quad) --
        const floatx4 r2 = *(const floatx4*)(bc + LDSF(2, nl, bq ^ nl));
        const floatx4 r4 = *(const floatx4*)(bc + LDSF(4, nl, bq ^ nl));
        const floatx4 r5 = *(const floatx4*)(bc + LDSF(5, nl, bq ^ nl));

        // -- fold + GEMV stores (normal stores; 4 waves' 64B segments merge in L2) --
        floatx4 o2 = r2    + g[0] * (acc[0] + acc[4] + bv);
        floatx4 o4 = r4    + g[1] * (acc[0] + acc[6] + bv);
        floatx4 o5 = r5    + g[3] * (acc[1] + acc[6] + bv)
                           + g[6] * (acc[3] + acc[5] + bv);
        floatx4 o6 = res6C + g[2] * (acc[0] + acc[7] + bv)
                           + g[4] * (acc[3] + acc[4] + bv)
                           + g[5] * (acc[2] + acc[5] + bv);
        float* op = out + tb + nl * 448 + bq * 4;
        *(floatx4*)(op + 2 * 64) = o2;
        *(floatx4*)(op + 4 * 64) = o4;
        *(floatx4*)(op + 5 * 64) = o5;
        *(floatx4*)(op + 6 * 64) = o6;

        // -- commit T+1 (issued one full body ago) into the other buffer --
        // compiler emits a counted vmcnt here: T+2's loads stay in flight.
        if (has1) {
            float* bn = buf[cur ^ 1];
            #pragma unroll
            for (int c = 0; c < 6; ++c)
                *(floatx4*)(bn + LDSF(c, bq, nl ^ bq)) = stgP[c];
        }
        __syncthreads();
        if (!has1) break;
        if (has2) {
            #pragma unroll
            for (int c = 0; c < 6; ++c) stgP[c] = stgN[c];
        }
        res6C = res6N;
        tile = nxt1;
        cur ^= 1;
    }
}

extern "C" void kernel_launch(void* const* d_in, const int* in_sizes, int n_in,
                              void* d_out, int out_size, void* d_ws, size_t ws_size,
                              hipStream_t stream) {
    const float* S     = (const float*)d_in[0];   // [B,7,64]
    const float* W     = (const float*)d_in[1];   // [64,128]
    const float* bias  = (const float*)d_in[2];   // [64]
    const float* gates = (const float*)d_in[3];   // [7]
    float* out = (float*)d_out;

    const int B  = in_sizes[0] / (7 * 64);        // 131072
    const int nt = B / 16;                        // 8192 tiles of 16 batches
    int grid = 768;                               // 3 blocks/CU, grid-stride
    if (grid > nt) grid = nt;
    fano_kernel<<<grid, 256, 0, stream>>>(S, W, bias, gates, out, nt);
}

// Round 6
// 447.600 us; speedup vs baseline: 1.0332x; 1.0196x over previous
//
#include <hip/hip_runtime.h>
#include <math.h>

// FanoCoupling, round 7 (resubmit; round-5 infra failure, no dispatch ran).
//
// Round-6 counter smoking gun: WRITE_SIZE stayed 2.1x ideal with NORMAL
// stores. Cause: z is split across waves, so each 128B output line of the
// GEMV colonies gets its two 64B halves from DIFFERENT waves; merging
// relied on L2 dirty residency (~10us) vs ~15us body time -> ~2x write
// amplification + RFO fetch. (Round 3, where one wave owned all z of a
// batch, had ideal WRITE -- same-wave adjacent-instruction halves merge.)
//
// Fix: pair half-lines in LDS. After the fold, stage o2/o4/o5/o6 into the
// DEAD colony-0..3 slots of buf[cur] (fully read before barrier#1; next
// tile stages into buf[cur^1]), then after barrier#2 each wave stores one
// whole colony with 4x256B contiguous segments per instruction -- every
// output line written by a single instruction. Copies {0,1,3} already
// full-line. 2 barriers/tile, LDS still 48KB -> 3 blocks/CU.
//
// Pipeline (unchanged): body(T) issues NT loads(T+2)->stgN, computes T,
// ds_writes stgP(T+1, issued a full body ago) -> buf[cur^1]; counted vmcnt
// keeps T+2's loads in flight across the barriers. res6 prefetch dist-1.
//
// Lines: O2=s2+g0*(U0+V1+b)  O4=s4+g1*(U0+V3+b)
//        O5=s5+g3*(U1+V3+b)+g6*(U4+V2+b)
//        O6=s6+g2*(U0+V5+b)+g4*(U4+V1+b)+g5*(U3+V2+b)
//        O0,O1,O3 = copies.

using bf16x8  = __attribute__((ext_vector_type(8))) __bf16;
using floatx4 = __attribute__((ext_vector_type(4))) float;

__device__ __forceinline__ bf16x8 cvt8(floatx4 a, floatx4 b) {
    bf16x8 r;
    r[0]=(__bf16)a[0]; r[1]=(__bf16)a[1]; r[2]=(__bf16)a[2]; r[3]=(__bf16)a[3];
    r[4]=(__bf16)b[0]; r[5]=(__bf16)b[1]; r[6]=(__bf16)b[2]; r[7]=(__bf16)b[3];
    return r;
}

// float index of 16B unit (c, row, slot) in one LDS buffer
#define LDSF(c, row, slot) ((((c) << 8) | ((row) << 4) | (slot)) << 2)

__global__ __launch_bounds__(256, 3)
void fano_kernel(const float* __restrict__ S,
                 const float* __restrict__ W,
                 const float* __restrict__ bias,
                 const float* __restrict__ gates,
                 float* __restrict__ out, int nt)
{
    __shared__ float buf[2][6144];    // 48 KiB total

    const int tid  = threadIdx.x;
    const int lane = tid & 63;
    const int w    = tid >> 6;        // wave = z-quarter (compute) / colony (store)
    const int nl   = lane & 15;       // batch (frag n)
    const int qg   = lane >> 4;       // k-quad / batch-subrow
    const int bq   = w * 4 + qg;      // staging/copy batch row; ALSO z-quad idx

    // ---- gates softmax (uniform) ----
    float g[7];
    {
        float mx = gates[0];
        #pragma unroll
        for (int i = 1; i < 7; ++i) mx = fmaxf(mx, gates[i]);
        float se = 0.f;
        #pragma unroll
        for (int i = 0; i < 7; ++i) { g[i] = __expf(gates[i] - mx); se += g[i]; }
        const float inv = 1.f / se;
        #pragma unroll
        for (int i = 0; i < 7; ++i) g[i] *= inv;
    }

    // ---- bias frag: z = bq*4 + r ----
    const floatx4 bv = *(const floatx4*)(bias + bq * 4);

    // ---- W frags (A operand): lane holds z=w*16+nl, k=h*32+qg*8+j ----
    bf16x8 wf[4];
    #pragma unroll
    for (int h = 0; h < 4; ++h) {
        const float* p = W + (w * 16 + nl) * 128 + h * 32 + qg * 8;
        wf[h] = cvt8(*(const floatx4*)p, *(const floatx4*)(p + 4));
    }

    // store-phase colony for this wave: {2,4,5,6}[w]
    const int gcol = (w == 0) ? 2 : (w == 1) ? 4 : (w == 2) ? 5 : 6;

    const long long st = gridDim.x;
    long long tile = blockIdx.x;
    if (tile >= nt) return;
    int cur = 0;

    // ---- prologue: stage tile into buf[0]; issue tile+st loads + res6(tile) ----
    {
        const float* sp = S + tile * 7168 + bq * 448;
        #pragma unroll
        for (int c = 0; c < 6; ++c) {
            floatx4 v = __builtin_nontemporal_load((const floatx4*)(sp + c * 64 + nl * 4));
            *(floatx4*)(&buf[0][LDSF(c, bq, nl ^ bq)]) = v;
        }
    }
    floatx4 stgP[6];
    if (tile + st < (long long)nt) {
        const float* sp = S + (tile + st) * 7168 + bq * 448;
        #pragma unroll
        for (int c = 0; c < 6; ++c)
            stgP[c] = __builtin_nontemporal_load((const floatx4*)(sp + c * 64 + nl * 4));
    }
    floatx4 res6C = __builtin_nontemporal_load(
        (const floatx4*)(S + tile * 7168 + nl * 448 + 384 + bq * 4));
    __syncthreads();

    for (;;) {
        const long long nxt1 = tile + st;
        const long long nxt2 = tile + 2 * st;
        const bool has1 = nxt1 < (long long)nt;
        const bool has2 = nxt2 < (long long)nt;
        const long long tb = tile * 7168;

        // -- issue distance-2 loads (in flight across this body AND barriers) --
        floatx4 stgN[6];
        if (has2) {
            const float* sp = S + nxt2 * 7168 + bq * 448;
            #pragma unroll
            for (int c = 0; c < 6; ++c)
                stgN[c] = __builtin_nontemporal_load((const floatx4*)(sp + c * 64 + nl * 4));
        }
        // -- distance-1 colony-6 residual for the NEXT body --
        floatx4 res6N;
        if (has1)
            res6N = __builtin_nontemporal_load(
                (const floatx4*)(S + nxt1 * 7168 + nl * 448 + 384 + bq * 4));

        const float* bc = buf[cur];

        // -- copies {0,1,3}: LDS -> coalesced store (4x256B/instr, full lines) --
        #pragma unroll
        for (int j = 0; j < 3; ++j) {
            const int c = (j == 2) ? 3 : j;
            floatx4 v = *(const floatx4*)(bc + LDSF(c, bq, nl ^ bq));
            *(floatx4*)(out + tb + bq * 448 + c * 64 + nl * 4) = v;
        }

        // -- MFMA: 2 k-phases, B-frags from swizzled LDS --
        floatx4 acc[8];
        #pragma unroll
        for (int s8 = 0; s8 < 8; ++s8) acc[s8] = (floatx4){0.f, 0.f, 0.f, 0.f};
        #pragma unroll
        for (int kb = 0; kb < 2; ++kb) {
            bf16x8 sb[6];
            const int u0 = kb * 8 + qg * 2;
            #pragma unroll
            for (int c = 0; c < 6; ++c) {
                floatx4 f0 = *(const floatx4*)(bc + LDSF(c, nl, (u0    ) ^ nl));
                floatx4 f1 = *(const floatx4*)(bc + LDSF(c, nl, (u0 + 1) ^ nl));
                sb[c] = cvt8(f0, f1);
            }
            acc[0] = __builtin_amdgcn_mfma_f32_16x16x32_bf16(wf[kb],     sb[0], acc[0], 0,0,0);
            acc[1] = __builtin_amdgcn_mfma_f32_16x16x32_bf16(wf[kb],     sb[1], acc[1], 0,0,0);
            acc[2] = __builtin_amdgcn_mfma_f32_16x16x32_bf16(wf[kb],     sb[3], acc[2], 0,0,0);
            acc[3] = __builtin_amdgcn_mfma_f32_16x16x32_bf16(wf[kb],     sb[4], acc[3], 0,0,0);
            acc[4] = __builtin_amdgcn_mfma_f32_16x16x32_bf16(wf[2 + kb], sb[1], acc[4], 0,0,0);
            acc[5] = __builtin_amdgcn_mfma_f32_16x16x32_bf16(wf[2 + kb], sb[2], acc[5], 0,0,0);
            acc[6] = __builtin_amdgcn_mfma_f32_16x16x32_bf16(wf[2 + kb], sb[3], acc[6], 0,0,0);
            acc[7] = __builtin_amdgcn_mfma_f32_16x16x32_bf16(wf[2 + kb], sb[5], acc[7], 0,0,0);
        }

        // -- residuals {2,4,5} in acc layout (row=nl batch, unit=bq z-quad) --
        const floatx4 r2 = *(const floatx4*)(bc + LDSF(2, nl, bq ^ nl));
        const floatx4 r4 = *(const floatx4*)(bc + LDSF(4, nl, bq ^ nl));
        const floatx4 r5 = *(const floatx4*)(bc + LDSF(5, nl, bq ^ nl));

        // -- fold (per-lane: batch nl, z = bq*4..bq*4+3) --
        floatx4 o2 = r2    + g[0] * (acc[0] + acc[4] + bv);
        floatx4 o4 = r4    + g[1] * (acc[0] + acc[6] + bv);
        floatx4 o5 = r5    + g[3] * (acc[1] + acc[6] + bv)
                           + g[6] * (acc[3] + acc[5] + bv);
        floatx4 o6 = res6C + g[2] * (acc[0] + acc[7] + bv)
                           + g[4] * (acc[3] + acc[4] + bv)
                           + g[5] * (acc[2] + acc[5] + bv);

        // -- barrier #1: all waves done READING buf[cur] (and prev stores done) --
        __syncthreads();

        // -- stage GEMV outputs into dead colony-0..3 slots of buf[cur] --
        //    row = nl (batch), slot = bq (z-quad), XOR-swizzled
        float* bo = buf[cur];
        *(floatx4*)(bo + LDSF(0, nl, bq ^ nl)) = o2;
        *(floatx4*)(bo + LDSF(1, nl, bq ^ nl)) = o4;
        *(floatx4*)(bo + LDSF(2, nl, bq ^ nl)) = o5;
        *(floatx4*)(bo + LDSF(3, nl, bq ^ nl)) = o6;

        // -- commit T+1 staging (issued one full body ago) into other buffer --
        //    counted vmcnt here: T+2's loads stay in flight.
        if (has1) {
            float* bn = buf[cur ^ 1];
            #pragma unroll
            for (int c = 0; c < 6; ++c)
                *(floatx4*)(bn + LDSF(c, bq, nl ^ bq)) = stgP[c];
        }

        // -- barrier #2: o-staging visible to all waves --
        __syncthreads();

        // -- GEMV stores: wave w stores colony gcol, 4x256B full lines/instr --
        #pragma unroll
        for (int j = 0; j < 4; ++j) {
            const int b = j * 4 + qg;                       // batch row
            floatx4 v = *(const floatx4*)(bo + LDSF(w, b, nl ^ b));
            *(floatx4*)(out + tb + b * 448 + gcol * 64 + nl * 4) = v;
        }

        if (!has1) break;
        if (has2) {
            #pragma unroll
            for (int c = 0; c < 6; ++c) stgP[c] = stgN[c];
        }
        res6C = res6N;
        tile = nxt1;
        cur ^= 1;
    }
}

extern "C" void kernel_launch(void* const* d_in, const int* in_sizes, int n_in,
                              void* d_out, int out_size, void* d_ws, size_t ws_size,
                              hipStream_t stream) {
    const float* S     = (const float*)d_in[0];   // [B,7,64]
    const float* W     = (const float*)d_in[1];   // [64,128]
    const float* bias  = (const float*)d_in[2];   // [64]
    const float* gates = (const float*)d_in[3];   // [7]
    float* out = (float*)d_out;

    const int B  = in_sizes[0] / (7 * 64);        // 131072
    const int nt = B / 16;                        // 8192 tiles of 16 batches
    int grid = 768;                               // 3 blocks/CU, grid-stride
    if (grid > nt) grid = nt;
    fano_kernel<<<grid, 256, 0, stream>>>(S, W, bias, gates, out, nt);
}